// Round 2
// baseline (331.334 us; speedup 1.0000x reference)
//
#include <hip/hip_runtime.h>
#include <hip/hip_bf16.h>
#include <stdint.h>

typedef __bf16 bf16_t;
typedef __bf16 bf16x4 __attribute__((ext_vector_type(4)));
typedef __bf16 bf16x8 __attribute__((ext_vector_type(8)));
typedef float  f32x4  __attribute__((ext_vector_type(4)));

#define AS1 __attribute__((address_space(1)))
#define AS3 __attribute__((address_space(3)))

// async global->LDS, 16B per lane; lds dest = wave-uniform base + lane*16
__device__ __forceinline__ void gld_lds16(const void* gp, void* lp) {
    __builtin_amdgcn_global_load_lds((const AS1 unsigned int*)gp,
                                     (AS3 unsigned int*)lp, 16, 0, 0);
}

__device__ __forceinline__ bf16_t bhi(float v) { return (bf16_t)v; }
__device__ __forceinline__ bf16_t blo(float v) {
    return (bf16_t)(v - (float)((bf16_t)v));
}

// ---------------------------------------------------------------------------
// Kernel 1: W fp32 -> bf16
// ---------------------------------------------------------------------------
__global__ __launch_bounds__(256) void wconv_kernel(const float* __restrict__ W,
                                                    bf16_t* __restrict__ Wb) {
    const int i = (blockIdx.x * 256 + threadIdx.x) * 4;
    const float4 f = *(const float4*)&W[i];
    bf16x4 v = { (bf16_t)f.x, (bf16_t)f.y, (bf16_t)f.z, (bf16_t)f.w };
    *(bf16x4*)&Wb[i] = v;
}

// ---------------------------------------------------------------------------
// Kernel 2: attention per (b,h).  L=64, E=128.  fp32 in, bf16 X out.
//
// Round-2 restructure: the limiter was MLP starvation (2.7 B/cy/CU vs ~10
// achievable; blocks front-load 98KB then go memory-silent; 3 blocks/CU).
//  - LDS 48KB -> 32KB: ONE 16KB K buffer staged twice (KH, then KL from
//    lo-half bf16 regs held across the KH passes: 16 VGPR).  V^T 16KB.
//    Ps overlays K; O stored directly to global (Ob eliminated; L2 merges
//    the 2B stores into full lines).
//  - Pass order (Qh*KH, Ql*KH, ..., Qh*KL) retires ql8 early: peak ~90 VGPR
//    -> __launch_bounds__(256,5): 5 blocks/CU (5 x 32KB = 160KB LDS exactly).
//  - V global loads issued MID-kernel (after KH passes, sched_barrier-pinned):
//    splits the HBM burst in two, de-herds traffic across resident blocks.
//  - Every phase consumes its own loads -> all 4 __syncthreads drain nothing.
//  - K staging now 4x ds_write_b128 w/ chunk-XOR swizzle: conflict-free
//    (kills the residual 2^21 conflict cycles from the b64 pattern).
// ---------------------------------------------------------------------------
__global__ __launch_bounds__(256, 5) void attn_kernel(const float* __restrict__ Q,
                                                      const float* __restrict__ K,
                                                      const float* __restrict__ V,
                                                      bf16_t* __restrict__ X) {
    // LDS plan (bytes):
    //   Kb : [0, 16384)      64x128 bf16 swz  (KH then KL) -> Ps overlay
    //   Vt : [16384, 32768)  128x64 bf16 swz  (V^T)
    __shared__ __align__(16) char smem[32768];
    bf16_t* Kb = (bf16_t*)smem;
    bf16_t* Vt = (bf16_t*)(smem + 16384);
    bf16_t* Ps = (bf16_t*)smem;             // 64x64 swz, wave-local rows

    const int bh    = blockIdx.x;          // b*16 + h
    const int b     = bh >> 4;
    const int h     = bh & 15;
    const int t     = threadIdx.x;
    const int w     = t >> 6;              // wave 0..3
    const int lane  = t & 63;
    const int row16 = lane & 15;
    const int quad  = lane >> 4;

    const float* Qg = Q + (size_t)bh * 8192;
    const float* Kg = K + (size_t)bh * 8192;
    const float* Vg = V + (size_t)bh * 8192;

    // ---- Q: per-lane direct load of this lane's A-fragments (hi+lo) ----
    bf16x8 qh8[4], ql8[4];
    {
        const float* qrow = Qg + (size_t)(16 * w + row16) * 128 + 8 * quad;
#pragma unroll
        for (int kc = 0; kc < 4; ++kc) {
            const float4 f0 = *(const float4*)&qrow[32 * kc];
            const float4 f1 = *(const float4*)&qrow[32 * kc + 4];
            const float f[8] = { f0.x, f0.y, f0.z, f0.w, f1.x, f1.y, f1.z, f1.w };
            bf16x8 hi, lo;
#pragma unroll
            for (int j = 0; j < 8; ++j) {
                const bf16_t hv = (bf16_t)f[j];
                hi[j] = hv;
                lo[j] = (bf16_t)(f[j] - (float)hv);
            }
            qh8[kc] = hi;
            ql8[kc] = lo;
        }
    }

    // ---- K: load fp32 row-stripe, write KH (b128, swizzled), hold lo regs ----
    // thread t -> row r = t>>2, cols [32*(t&3), +32) = 4 chunks of 8.
    const int r   = t >> 2;
    const int c0q = (t & 3) * 4;          // chunk index base (c0/8)
    const int rsw = r & 7;
    bf16x8 klo[4];
    int kaddr[4];
#pragma unroll
    for (int jc = 0; jc < 4; ++jc)
        kaddr[jc] = r * 128 + (((c0q + jc) ^ rsw) << 3);
    {
#pragma unroll
        for (int jc = 0; jc < 4; ++jc) {
            const float4 f0 = *(const float4*)&Kg[r * 128 + 8 * (c0q + jc)];
            const float4 f1 = *(const float4*)&Kg[r * 128 + 8 * (c0q + jc) + 4];
            const float f[8] = { f0.x, f0.y, f0.z, f0.w, f1.x, f1.y, f1.z, f1.w };
            bf16x8 hi, lo;
#pragma unroll
            for (int j = 0; j < 8; ++j) {
                const bf16_t hv = (bf16_t)f[j];
                hi[j] = hv;
                lo[j] = (bf16_t)(f[j] - (float)hv);
            }
            *(bf16x8*)&Kb[kaddr[jc]] = hi;
            klo[jc] = lo;
        }
    }

    __syncthreads();   // B1: KH staged (no outstanding vmcnt)

    // ---- scores vs KH: Qh*KH then Ql*KH (ql8 dies here) ----
    f32x4 accS[4];
#pragma unroll
    for (int ni = 0; ni < 4; ++ni) accS[ni] = (f32x4){0.f, 0.f, 0.f, 0.f};
    const int bsw = row16 & 7;

#define SPASS(AREG)                                                            \
    {                                                                          \
        _Pragma("unroll")                                                      \
        for (int kc = 0; kc < 4; ++kc) {                                       \
            const bf16x8 a = AREG[kc];                                         \
            _Pragma("unroll")                                                  \
            for (int ni = 0; ni < 4; ++ni) {                                   \
                const bf16x8 bb = *(const bf16x8*)&Kb[(16 * ni + row16) * 128  \
                                       + ((((4 * kc + quad) ^ bsw)) << 3)];    \
                accS[ni] = __builtin_amdgcn_mfma_f32_16x16x32_bf16(a, bb, accS[ni], 0, 0, 0); \
            }                                                                  \
        }                                                                      \
    }

    __builtin_amdgcn_s_setprio(1);
    SPASS(qh8)      // Qh * Kh
    SPASS(ql8)      // Ql * Kh
    __builtin_amdgcn_s_setprio(0);

    // ---- V: issue loads NOW (mid-kernel burst), convert, stage Vt ----
    __builtin_amdgcn_sched_barrier(0);
    {
        const int s = lane;
#pragma unroll
        for (int j = 0; j < 8; ++j) {
            const int d0 = 32 * w + 4 * j;
            const float4 f = *(const float4*)&Vg[(size_t)s * 128 + d0];
            const float ff[4] = { f.x, f.y, f.z, f.w };
#pragma unroll
            for (int i = 0; i < 4; ++i) {
                const int d = d0 + i;
                Vt[d * 64 + ((((s >> 3) ^ (d & 7))) << 3) + (s & 7)] = (bf16_t)ff[i];
            }
        }
    }

    __syncthreads();   // B2: all KH reads done -> Kb reusable (nothing outstanding)

    // ---- restage K: KL from held lo regs ----
#pragma unroll
    for (int jc = 0; jc < 4; ++jc)
        *(bf16x8*)&Kb[kaddr[jc]] = klo[jc];

    __syncthreads();   // B3: KL staged

    __builtin_amdgcn_s_setprio(1);
    SPASS(qh8)      // Qh * Kl   ((l,l) term ~2^-18 relative — negligible)
    __builtin_amdgcn_s_setprio(0);

    // ---- softmax fully in-register ----
    // lane holds S[l=16w+4q+rr][s=16ni+row16]
    float e[4][4];      // e[ni][rr]
    float inv_[4];
    const float cs = 0.1f * 1.44269504088896f;   // scale * log2(e)
#pragma unroll
    for (int rr = 0; rr < 4; ++rr) {
        float m = fmaxf(fmaxf(accS[0][rr], accS[1][rr]),
                        fmaxf(accS[2][rr], accS[3][rr]));
        m = fmaxf(m, __shfl_xor(m, 1));
        m = fmaxf(m, __shfl_xor(m, 2));
        m = fmaxf(m, __shfl_xor(m, 4));
        m = fmaxf(m, __shfl_xor(m, 8));
        float s0 = 0.f;
#pragma unroll
        for (int ni = 0; ni < 4; ++ni) {
            const float ev = exp2f((accS[ni][rr] - m) * cs);
            e[ni][rr] = ev;
            s0 += ev;
        }
        s0 += __shfl_xor(s0, 1);
        s0 += __shfl_xor(s0, 2);
        s0 += __shfl_xor(s0, 4);
        s0 += __shfl_xor(s0, 8);
        inv_[rr] = 1.0f / s0;    // folded in after PV
    }

    __syncthreads();   // B4: all KL reads done -> Ps overlay safe; Vt published

    // ---- P (unnormalized, bf16) -> Ps (Kb region, wave-local rows) ----
#pragma unroll
    for (int rr = 0; rr < 4; ++rr) {
        const int l   = 16 * w + 4 * quad + rr;
        const int lsw = l & 7;
#pragma unroll
        for (int ni = 0; ni < 4; ++ni) {
            const int s = 16 * ni + row16;
            Ps[l * 64 + ((((s >> 3) ^ lsw)) << 3) + (s & 7)] = (bf16_t)e[ni][rr];
        }
    }
    asm volatile("s_waitcnt lgkmcnt(0)" ::: "memory");
    __builtin_amdgcn_sched_barrier(0);

    // ---- O[l,d] = sum_s P[l,s] V[s,d] ----
    f32x4 accO[8];
#pragma unroll
    for (int ni = 0; ni < 8; ++ni) accO[ni] = (f32x4){0.f, 0.f, 0.f, 0.f};
    __builtin_amdgcn_s_setprio(1);
#pragma unroll
    for (int kb = 0; kb < 2; ++kb) {
        const bf16x8 a = *(const bf16x8*)&Ps[(16 * w + row16) * 64
                               + ((((4 * kb + quad) ^ bsw)) << 3)];
#pragma unroll
        for (int ni = 0; ni < 8; ++ni) {
            const bf16x8 bb = *(const bf16x8*)&Vt[(16 * ni + row16) * 64
                                   + ((((4 * kb + quad) ^ bsw)) << 3)];
            accO[ni] = __builtin_amdgcn_mfma_f32_16x16x32_bf16(a, bb, accO[ni], 0, 0, 0);
        }
    }
    __builtin_amdgcn_s_setprio(0);

    // ---- direct global store, scaled by 1/sum (L2 merges 2B stores) ----
    {
        const int lbase = 16 * w + 4 * quad;
        bf16_t* Xb = X + (size_t)b * 131072 + (size_t)h * 128;
#pragma unroll
        for (int ni = 0; ni < 8; ++ni)
#pragma unroll
            for (int rr = 0; rr < 4; ++rr)
                Xb[(size_t)(lbase + rr) * 2048 + 16 * ni + row16] =
                    (bf16_t)(accO[ni][rr] * inv_[rr]);
    }
}

// ---------------------------------------------------------------------------
// Kernel 3: out[m,n] = sum_k X[m,k] Wb[n,k] + bias[n]  (M=8192,N=2048,K=2048)
// 128x128 tile, BK=64, 256 thr, 4 blocks/CU, global_load_lds width 16.
// LDS tile [128 rows][8 chunks of 16B] with XOR swizzle p = q ^ (row&7):
// fragment reads hit all 32 banks evenly (conflict-free).
// Grid x = M-tiles so each XCD's X slice (4 MiB) stays L2-resident.
// ---------------------------------------------------------------------------
__global__ __launch_bounds__(256, 4) void gemm_kernel(const bf16_t* __restrict__ X,
                                                      const bf16_t* __restrict__ Wb,
                                                      const float* __restrict__ bias,
                                                      float* __restrict__ out) {
    __shared__ bf16_t As[128 * 64];   // 16 KiB
    __shared__ bf16_t Bs[128 * 64];   // 16 KiB

    const int t    = threadIdx.x;
    const int w    = t >> 6;
    const int lane = t & 63;
    const int row16 = lane & 15;
    const int quad  = lane >> 4;
    const int m0 = blockIdx.x * 128;   // x = M (XCD locality for X)
    const int n0 = blockIdx.y * 128;
    const int wm = w >> 1;             // 2x2 wave grid, each wave 64x64
    const int wn = w & 1;

    // staging: wave w stages rows [32w,32w+32) of each tile, 4 insts of 8 rows.
    // lane -> (row8 = lane>>3, q = lane&7); global col swizzled: 8*(q ^ row8)
    const int row8 = lane >> 3;
    const int scol = 8 * ((lane & 7) ^ (row8 & 7));
    const bf16_t* gA = X  + (size_t)(m0 + 32 * w + row8) * 2048 + scol;
    const bf16_t* gB = Wb + (size_t)(n0 + 32 * w + row8) * 2048 + scol;
    bf16_t* lA = &As[(32 * w) * 64];
    bf16_t* lB = &Bs[(32 * w) * 64];

    // fragment read offsets (elements), swizzled: row*64 + 8*((4*kk+quad)^(row&7))
    const int sw = row16 & 7;
    int aoff[4][2], boff[4][2];
#pragma unroll
    for (int mi = 0; mi < 4; ++mi)
#pragma unroll
        for (int kk = 0; kk < 2; ++kk) {
            const int ar = 64 * wm + 16 * mi + row16;
            const int br = 64 * wn + 16 * mi + row16;
            aoff[mi][kk] = ar * 64 + 8 * ((4 * kk + quad) ^ sw);
            boff[mi][kk] = br * 64 + 8 * ((4 * kk + quad) ^ sw);
        }

    f32x4 acc[4][4];
#pragma unroll
    for (int mi = 0; mi < 4; ++mi)
#pragma unroll
        for (int ni = 0; ni < 4; ++ni) acc[mi][ni] = (f32x4){0.f, 0.f, 0.f, 0.f};

    for (int kb = 0; kb < 32; ++kb) {
        const int k0 = kb * 64;
        __syncthreads();                       // previous compute done before overwrite
#pragma unroll
        for (int i = 0; i < 4; ++i) {
            gld_lds16(gA + (size_t)(8 * i) * 2048 + k0, lA + (8 * i) * 64);
            gld_lds16(gB + (size_t)(8 * i) * 2048 + k0, lB + (8 * i) * 64);
        }
        __syncthreads();                       // staged (compiler drains vmcnt)

#pragma unroll
        for (int kk = 0; kk < 2; ++kk) {
            bf16x8 a[4], bb[4];
#pragma unroll
            for (int mi = 0; mi < 4; ++mi) a[mi]  = *(const bf16x8*)&As[aoff[mi][kk]];
#pragma unroll
            for (int ni = 0; ni < 4; ++ni) bb[ni] = *(const bf16x8*)&Bs[boff[ni][kk]];
#pragma unroll
            for (int mi = 0; mi < 4; ++mi)
#pragma unroll
                for (int ni = 0; ni < 4; ++ni)
                    acc[mi][ni] = __builtin_amdgcn_mfma_f32_16x16x32_bf16(a[mi], bb[ni], acc[mi][ni], 0, 0, 0);
        }
    }

    // epilogue: add bias, store FP32
    const int nb = n0 + 64 * wn;
    float br[4];
#pragma unroll
    for (int ni = 0; ni < 4; ++ni) br[ni] = bias[nb + 16 * ni + row16];
#pragma unroll
    for (int mi = 0; mi < 4; ++mi)
#pragma unroll
        for (int ni = 0; ni < 4; ++ni)
#pragma unroll
            for (int rr = 0; rr < 4; ++rr) {
                const int m = m0 + 64 * wm + 16 * mi + 4 * quad + rr;
                const int n = nb + 16 * ni + row16;
                out[(size_t)m * 2048 + n] = acc[mi][ni][rr] + br[ni];
            }
}

// ---------------------------------------------------------------------------
extern "C" void kernel_launch(void* const* d_in, const int* in_sizes, int n_in,
                              void* d_out, int out_size, void* d_ws, size_t ws_size,
                              hipStream_t stream) {
    const float* Q    = (const float*)d_in[0];
    const float* K    = (const float*)d_in[1];
    const float* V    = (const float*)d_in[2];
    const float* W    = (const float*)d_in[3];
    const float* bias = (const float*)d_in[4];

    bf16_t* Xws = (bf16_t*)d_ws;                                    // 32 MiB
    bf16_t* Wb  = (bf16_t*)((char*)d_ws + (size_t)8192 * 2048 * 2); // 8 MiB
    float*  out = (float*)d_out;

    wconv_kernel<<<4096, 256, 0, stream>>>(W, Wb);
    attn_kernel<<<2048, 256, 0, stream>>>(Q, K, V, Xws);
    gemm_kernel<<<dim3(64, 16), 256, 0, stream>>>(Xws, Wb, bias, out);
}

// Round 3
// 330.894 us; speedup vs baseline: 1.0013x; 1.0013x over previous
//
#include <hip/hip_runtime.h>
#include <hip/hip_bf16.h>
#include <stdint.h>

typedef __bf16 bf16_t;
typedef __bf16 bf16x4 __attribute__((ext_vector_type(4)));
typedef __bf16 bf16x8 __attribute__((ext_vector_type(8)));
typedef float  f32x4  __attribute__((ext_vector_type(4)));

#define AS1 __attribute__((address_space(1)))
#define AS3 __attribute__((address_space(3)))

// async global->LDS, 16B per lane; lds dest = wave-uniform base + lane*16
__device__ __forceinline__ void gld_lds16(const void* gp, void* lp) {
    __builtin_amdgcn_global_load_lds((const AS1 unsigned int*)gp,
                                     (AS3 unsigned int*)lp, 16, 0, 0);
}

__device__ __forceinline__ bf16_t bhi(float v) { return (bf16_t)v; }
__device__ __forceinline__ bf16_t blo(float v) {
    return (bf16_t)(v - (float)((bf16_t)v));
}

// ---------------------------------------------------------------------------
// Kernel 1: W fp32 -> bf16
// ---------------------------------------------------------------------------
__global__ __launch_bounds__(256) void wconv_kernel(const float* __restrict__ W,
                                                    bf16_t* __restrict__ Wb) {
    const int i = (blockIdx.x * 256 + threadIdx.x) * 4;
    const float4 f = *(const float4*)&W[i];
    bf16x4 v = { (bf16_t)f.x, (bf16_t)f.y, (bf16_t)f.z, (bf16_t)f.w };
    *(bf16x4*)&Wb[i] = v;
}

// ---------------------------------------------------------------------------
// Kernel 2: attention per (b,h).  L=64, E=128.  fp32 in, bf16 X out.
//
// Round-3: round-2 structure (5 blocks/CU, single K buffer staged twice,
// mid-kernel V burst — these raised achieved BW 1.65->2.7 TB/s) + round-1
// store path (LDS Ob coalescing buffer + bf16x8 16B stores — WRITE_SIZE
// 33MB, vs round-2's direct 2B stores which caused 141MB write + 53MB RMW
// fetch amplification).  Ob overlays Vt (dead after PV) behind one extra
// __syncthreads.
// ---------------------------------------------------------------------------
__global__ __launch_bounds__(256, 5) void attn_kernel(const float* __restrict__ Q,
                                                      const float* __restrict__ K,
                                                      const float* __restrict__ V,
                                                      bf16_t* __restrict__ X) {
    // LDS plan (bytes):
    //   Kb : [0, 16384)      64x128 bf16 swz  (KH then KL) -> Ps overlay
    //   Vt : [16384, 32768)  128x64 bf16 swz  (V^T)        -> Ob overlay
    __shared__ __align__(16) char smem[32768];
    bf16_t* Kb = (bf16_t*)smem;
    bf16_t* Vt = (bf16_t*)(smem + 16384);
    bf16_t* Ps = (bf16_t*)smem;             // 64x64 swz, wave-local rows
    bf16_t* Ob = (bf16_t*)(smem + 16384);   // 64x128 swz, wave-local rows

    const int bh    = blockIdx.x;          // b*16 + h
    const int b     = bh >> 4;
    const int h     = bh & 15;
    const int t     = threadIdx.x;
    const int w     = t >> 6;              // wave 0..3
    const int lane  = t & 63;
    const int row16 = lane & 15;
    const int quad  = lane >> 4;

    const float* Qg = Q + (size_t)bh * 8192;
    const float* Kg = K + (size_t)bh * 8192;
    const float* Vg = V + (size_t)bh * 8192;

    // ---- Q: per-lane direct load of this lane's A-fragments (hi+lo) ----
    bf16x8 qh8[4], ql8[4];
    {
        const float* qrow = Qg + (size_t)(16 * w + row16) * 128 + 8 * quad;
#pragma unroll
        for (int kc = 0; kc < 4; ++kc) {
            const float4 f0 = *(const float4*)&qrow[32 * kc];
            const float4 f1 = *(const float4*)&qrow[32 * kc + 4];
            const float f[8] = { f0.x, f0.y, f0.z, f0.w, f1.x, f1.y, f1.z, f1.w };
            bf16x8 hi, lo;
#pragma unroll
            for (int j = 0; j < 8; ++j) {
                const bf16_t hv = (bf16_t)f[j];
                hi[j] = hv;
                lo[j] = (bf16_t)(f[j] - (float)hv);
            }
            qh8[kc] = hi;
            ql8[kc] = lo;
        }
    }

    // ---- K: load fp32 row-stripe, write KH (b128, swizzled), hold lo regs ----
    // thread t -> row r = t>>2, cols [32*(t&3), +32) = 4 chunks of 8.
    const int r   = t >> 2;
    const int c0q = (t & 3) * 4;          // chunk index base (c0/8)
    const int rsw = r & 7;
    bf16x8 klo[4];
    int kaddr[4];
#pragma unroll
    for (int jc = 0; jc < 4; ++jc)
        kaddr[jc] = r * 128 + (((c0q + jc) ^ rsw) << 3);
    {
#pragma unroll
        for (int jc = 0; jc < 4; ++jc) {
            const float4 f0 = *(const float4*)&Kg[r * 128 + 8 * (c0q + jc)];
            const float4 f1 = *(const float4*)&Kg[r * 128 + 8 * (c0q + jc) + 4];
            const float f[8] = { f0.x, f0.y, f0.z, f0.w, f1.x, f1.y, f1.z, f1.w };
            bf16x8 hi, lo;
#pragma unroll
            for (int j = 0; j < 8; ++j) {
                const bf16_t hv = (bf16_t)f[j];
                hi[j] = hv;
                lo[j] = (bf16_t)(f[j] - (float)hv);
            }
            *(bf16x8*)&Kb[kaddr[jc]] = hi;
            klo[jc] = lo;
        }
    }

    __syncthreads();   // B1: KH staged

    // ---- scores vs KH: Qh*KH then Ql*KH (ql8 dies here) ----
    f32x4 accS[4];
#pragma unroll
    for (int ni = 0; ni < 4; ++ni) accS[ni] = (f32x4){0.f, 0.f, 0.f, 0.f};
    const int bsw = row16 & 7;

#define SPASS(AREG)                                                            \
    {                                                                          \
        _Pragma("unroll")                                                      \
        for (int kc = 0; kc < 4; ++kc) {                                       \
            const bf16x8 a = AREG[kc];                                         \
            _Pragma("unroll")                                                  \
            for (int ni = 0; ni < 4; ++ni) {                                   \
                const bf16x8 bb = *(const bf16x8*)&Kb[(16 * ni + row16) * 128  \
                                       + ((((4 * kc + quad) ^ bsw)) << 3)];    \
                accS[ni] = __builtin_amdgcn_mfma_f32_16x16x32_bf16(a, bb, accS[ni], 0, 0, 0); \
            }                                                                  \
        }                                                                      \
    }

    __builtin_amdgcn_s_setprio(1);
    SPASS(qh8)      // Qh * Kh
    SPASS(ql8)      // Ql * Kh
    __builtin_amdgcn_s_setprio(0);

    // ---- V: issue loads NOW (mid-kernel burst), convert, stage Vt ----
    __builtin_amdgcn_sched_barrier(0);
    {
        const int s = lane;
#pragma unroll
        for (int j = 0; j < 8; ++j) {
            const int d0 = 32 * w + 4 * j;
            const float4 f = *(const float4*)&Vg[(size_t)s * 128 + d0];
            const float ff[4] = { f.x, f.y, f.z, f.w };
#pragma unroll
            for (int i = 0; i < 4; ++i) {
                const int d = d0 + i;
                Vt[d * 64 + ((((s >> 3) ^ (d & 7))) << 3) + (s & 7)] = (bf16_t)ff[i];
            }
        }
    }

    __syncthreads();   // B2: all KH reads done -> Kb reusable

    // ---- restage K: KL from held lo regs ----
#pragma unroll
    for (int jc = 0; jc < 4; ++jc)
        *(bf16x8*)&Kb[kaddr[jc]] = klo[jc];

    __syncthreads();   // B3: KL staged

    __builtin_amdgcn_s_setprio(1);
    SPASS(qh8)      // Qh * Kl   ((l,l) term ~2^-18 relative — negligible)
    __builtin_amdgcn_s_setprio(0);

    // ---- softmax fully in-register ----
    // lane holds S[l=16w+4q+rr][s=16ni+row16]
    float e[4][4];      // e[ni][rr]
    float inv_[4];
    const float cs = 0.1f * 1.44269504088896f;   // scale * log2(e)
#pragma unroll
    for (int rr = 0; rr < 4; ++rr) {
        float m = fmaxf(fmaxf(accS[0][rr], accS[1][rr]),
                        fmaxf(accS[2][rr], accS[3][rr]));
        m = fmaxf(m, __shfl_xor(m, 1));
        m = fmaxf(m, __shfl_xor(m, 2));
        m = fmaxf(m, __shfl_xor(m, 4));
        m = fmaxf(m, __shfl_xor(m, 8));
        float s0 = 0.f;
#pragma unroll
        for (int ni = 0; ni < 4; ++ni) {
            const float ev = exp2f((accS[ni][rr] - m) * cs);
            e[ni][rr] = ev;
            s0 += ev;
        }
        s0 += __shfl_xor(s0, 1);
        s0 += __shfl_xor(s0, 2);
        s0 += __shfl_xor(s0, 4);
        s0 += __shfl_xor(s0, 8);
        inv_[rr] = 1.0f / s0;    // folded in after PV
    }

    __syncthreads();   // B4: all KL reads done -> Ps overlay safe; Vt published

    // ---- P (unnormalized, bf16) -> Ps (Kb region, wave-local rows) ----
#pragma unroll
    for (int rr = 0; rr < 4; ++rr) {
        const int l   = 16 * w + 4 * quad + rr;
        const int lsw = l & 7;
#pragma unroll
        for (int ni = 0; ni < 4; ++ni) {
            const int s = 16 * ni + row16;
            Ps[l * 64 + ((((s >> 3) ^ lsw)) << 3) + (s & 7)] = (bf16_t)e[ni][rr];
        }
    }
    asm volatile("s_waitcnt lgkmcnt(0)" ::: "memory");
    __builtin_amdgcn_sched_barrier(0);

    // ---- O[l,d] = sum_s P[l,s] V[s,d] ----
    f32x4 accO[8];
#pragma unroll
    for (int ni = 0; ni < 8; ++ni) accO[ni] = (f32x4){0.f, 0.f, 0.f, 0.f};
    __builtin_amdgcn_s_setprio(1);
#pragma unroll
    for (int kb = 0; kb < 2; ++kb) {
        const bf16x8 a = *(const bf16x8*)&Ps[(16 * w + row16) * 64
                               + ((((4 * kb + quad) ^ bsw)) << 3)];
#pragma unroll
        for (int ni = 0; ni < 8; ++ni) {
            const bf16x8 bb = *(const bf16x8*)&Vt[(16 * ni + row16) * 64
                                   + ((((4 * kb + quad) ^ bsw)) << 3)];
            accO[ni] = __builtin_amdgcn_mfma_f32_16x16x32_bf16(a, bb, accO[ni], 0, 0, 0);
        }
    }
    __builtin_amdgcn_s_setprio(0);

    __syncthreads();   // B5: all PV reads of Vt done -> Ob overlay safe

    // ---- O -> Ob (Vt region, wave-local rows), scale by 1/sum ----
#pragma unroll
    for (int ni = 0; ni < 8; ++ni)
#pragma unroll
        for (int rr = 0; rr < 4; ++rr) {
            const int l = 16 * w + 4 * quad + rr;   // l&3 == rr
            const int d = 16 * ni + row16;
            Ob[l * 128 + ((((d >> 3) ^ (5 * rr))) << 3) + (d & 7)] =
                (bf16_t)(accO[ni][rr] * inv_[rr]);
        }
    asm volatile("s_waitcnt lgkmcnt(0)" ::: "memory");
    __builtin_amdgcn_sched_barrier(0);

    // ---- coalesced store of this wave's 16 rows (16B per lane) ----
    {
        const int lr = 16 * w + (lane >> 2);
        bf16_t* Xrow = X + (size_t)b * 131072 + (size_t)h * 128 + (size_t)lr * 2048;
#pragma unroll
        for (int jj = 0; jj < 4; ++jj) {
            const int c8 = (lane & 3) + 4 * jj;
            const bf16x8 v = *(const bf16x8*)&Ob[lr * 128 + ((c8 ^ (5 * (lr & 3))) << 3)];
            *(bf16x8*)&Xrow[8 * c8] = v;
        }
    }
}

// ---------------------------------------------------------------------------
// Kernel 3: out[m,n] = sum_k X[m,k] Wb[n,k] + bias[n]  (M=8192,N=2048,K=2048)
// 128x128 tile, BK=64, 256 thr, 4 blocks/CU, global_load_lds width 16.
// LDS tile [128 rows][8 chunks of 16B] with XOR swizzle p = q ^ (row&7):
// fragment reads hit all 32 banks evenly (conflict-free).
// Grid x = M-tiles so each XCD's X slice (4 MiB) stays L2-resident.
// ---------------------------------------------------------------------------
__global__ __launch_bounds__(256, 4) void gemm_kernel(const bf16_t* __restrict__ X,
                                                      const bf16_t* __restrict__ Wb,
                                                      const float* __restrict__ bias,
                                                      float* __restrict__ out) {
    __shared__ bf16_t As[128 * 64];   // 16 KiB
    __shared__ bf16_t Bs[128 * 64];   // 16 KiB

    const int t    = threadIdx.x;
    const int w    = t >> 6;
    const int lane = t & 63;
    const int row16 = lane & 15;
    const int quad  = lane >> 4;
    const int m0 = blockIdx.x * 128;   // x = M (XCD locality for X)
    const int n0 = blockIdx.y * 128;
    const int wm = w >> 1;             // 2x2 wave grid, each wave 64x64
    const int wn = w & 1;

    // staging: wave w stages rows [32w,32w+32) of each tile, 4 insts of 8 rows.
    // lane -> (row8 = lane>>3, q = lane&7); global col swizzled: 8*(q ^ row8)
    const int row8 = lane >> 3;
    const int scol = 8 * ((lane & 7) ^ (row8 & 7));
    const bf16_t* gA = X  + (size_t)(m0 + 32 * w + row8) * 2048 + scol;
    const bf16_t* gB = Wb + (size_t)(n0 + 32 * w + row8) * 2048 + scol;
    bf16_t* lA = &As[(32 * w) * 64];
    bf16_t* lB = &Bs[(32 * w) * 64];

    // fragment read offsets (elements), swizzled: row*64 + 8*((4*kk+quad)^(row&7))
    const int sw = row16 & 7;
    int aoff[4][2], boff[4][2];
#pragma unroll
    for (int mi = 0; mi < 4; ++mi)
#pragma unroll
        for (int kk = 0; kk < 2; ++kk) {
            const int ar = 64 * wm + 16 * mi + row16;
            const int br = 64 * wn + 16 * mi + row16;
            aoff[mi][kk] = ar * 64 + 8 * ((4 * kk + quad) ^ sw);
            boff[mi][kk] = br * 64 + 8 * ((4 * kk + quad) ^ sw);
        }

    f32x4 acc[4][4];
#pragma unroll
    for (int mi = 0; mi < 4; ++mi)
#pragma unroll
        for (int ni = 0; ni < 4; ++ni) acc[mi][ni] = (f32x4){0.f, 0.f, 0.f, 0.f};

    for (int kb = 0; kb < 32; ++kb) {
        const int k0 = kb * 64;
        __syncthreads();                       // previous compute done before overwrite
#pragma unroll
        for (int i = 0; i < 4; ++i) {
            gld_lds16(gA + (size_t)(8 * i) * 2048 + k0, lA + (8 * i) * 64);
            gld_lds16(gB + (size_t)(8 * i) * 2048 + k0, lB + (8 * i) * 64);
        }
        __syncthreads();                       // staged (compiler drains vmcnt)

#pragma unroll
        for (int kk = 0; kk < 2; ++kk) {
            bf16x8 a[4], bb[4];
#pragma unroll
            for (int mi = 0; mi < 4; ++mi) a[mi]  = *(const bf16x8*)&As[aoff[mi][kk]];
#pragma unroll
            for (int ni = 0; ni < 4; ++ni) bb[ni] = *(const bf16x8*)&Bs[boff[ni][kk]];
#pragma unroll
            for (int mi = 0; mi < 4; ++mi)
#pragma unroll
                for (int ni = 0; ni < 4; ++ni)
                    acc[mi][ni] = __builtin_amdgcn_mfma_f32_16x16x32_bf16(a[mi], bb[ni], acc[mi][ni], 0, 0, 0);
        }
    }

    // epilogue: add bias, store FP32
    const int nb = n0 + 64 * wn;
    float br[4];
#pragma unroll
    for (int ni = 0; ni < 4; ++ni) br[ni] = bias[nb + 16 * ni + row16];
#pragma unroll
    for (int mi = 0; mi < 4; ++mi)
#pragma unroll
        for (int ni = 0; ni < 4; ++ni)
#pragma unroll
            for (int rr = 0; rr < 4; ++rr) {
                const int m = m0 + 64 * wm + 16 * mi + 4 * quad + rr;
                const int n = nb + 16 * ni + row16;
                out[(size_t)m * 2048 + n] = acc[mi][ni][rr] + br[ni];
            }
}

// ---------------------------------------------------------------------------
extern "C" void kernel_launch(void* const* d_in, const int* in_sizes, int n_in,
                              void* d_out, int out_size, void* d_ws, size_t ws_size,
                              hipStream_t stream) {
    const float* Q    = (const float*)d_in[0];
    const float* K    = (const float*)d_in[1];
    const float* V    = (const float*)d_in[2];
    const float* W    = (const float*)d_in[3];
    const float* bias = (const float*)d_in[4];

    bf16_t* Xws = (bf16_t*)d_ws;                                    // 32 MiB
    bf16_t* Wb  = (bf16_t*)((char*)d_ws + (size_t)8192 * 2048 * 2); // 8 MiB
    float*  out = (float*)d_out;

    wconv_kernel<<<4096, 256, 0, stream>>>(W, Wb);
    attn_kernel<<<2048, 256, 0, stream>>>(Q, K, V, Xws);
    gemm_kernel<<<dim3(64, 16), 256, 0, stream>>>(Xws, Wb, bias, out);
}

// Round 4
// 305.336 us; speedup vs baseline: 1.0851x; 1.0837x over previous
//
#include <hip/hip_runtime.h>
#include <hip/hip_bf16.h>
#include <stdint.h>

typedef __bf16 bf16_t;
typedef __bf16 bf16x4 __attribute__((ext_vector_type(4)));
typedef __bf16 bf16x8 __attribute__((ext_vector_type(8)));
typedef float  f32x4  __attribute__((ext_vector_type(4)));

#define AS1 __attribute__((address_space(1)))
#define AS3 __attribute__((address_space(3)))

// async global->LDS, 16B per lane; lds dest = wave-uniform base + lane*16
__device__ __forceinline__ void gld_lds16(const void* gp, void* lp) {
    __builtin_amdgcn_global_load_lds((const AS1 unsigned int*)gp,
                                     (AS3 unsigned int*)lp, 16, 0, 0);
}

__device__ __forceinline__ bf16_t bhi(float v) { return (bf16_t)v; }
__device__ __forceinline__ bf16_t blo(float v) {
    return (bf16_t)(v - (float)((bf16_t)v));
}

// ---------------------------------------------------------------------------
// Kernel 1: W fp32 -> bf16
// ---------------------------------------------------------------------------
__global__ __launch_bounds__(256) void wconv_kernel(const float* __restrict__ W,
                                                    bf16_t* __restrict__ Wb) {
    const int i = (blockIdx.x * 256 + threadIdx.x) * 4;
    const float4 f = *(const float4*)&W[i];
    bf16x4 v = { (bf16_t)f.x, (bf16_t)f.y, (bf16_t)f.z, (bf16_t)f.w };
    *(bf16x4*)&Wb[i] = v;
}

// ---------------------------------------------------------------------------
// Kernel 2: attention per (b,h).  L=64, E=128.  fp32 in, bf16 X out.
//
// Round-4: round-3 structure, ONE change: __launch_bounds__(256,5) -> (256,4).
// Bound=5 capped the allocator at 48 VGPRs; the kernel's live set (~100:
// qh8/ql8/klo bf16x8 + accS/accO + V-staging in flight) spilled ~200B/thread
// to scratch = +110MB HBM write +54MB re-read (WRITE_SIZE 143MB vs 33MB
// ideal), serializing everything.  Bound=4 -> cap ~128 VGPR, zero spill,
// 4 blocks/CU (128KB LDS), still above round-1's 3 blocks/CU.
// ---------------------------------------------------------------------------
__global__ __launch_bounds__(256, 4) void attn_kernel(const float* __restrict__ Q,
                                                      const float* __restrict__ K,
                                                      const float* __restrict__ V,
                                                      bf16_t* __restrict__ X) {
    // LDS plan (bytes):
    //   Kb : [0, 16384)      64x128 bf16 swz  (KH then KL) -> Ps overlay
    //   Vt : [16384, 32768)  128x64 bf16 swz  (V^T)        -> Ob overlay
    __shared__ __align__(16) char smem[32768];
    bf16_t* Kb = (bf16_t*)smem;
    bf16_t* Vt = (bf16_t*)(smem + 16384);
    bf16_t* Ps = (bf16_t*)smem;             // 64x64 swz, wave-local rows
    bf16_t* Ob = (bf16_t*)(smem + 16384);   // 64x128 swz, wave-local rows

    const int bh    = blockIdx.x;          // b*16 + h
    const int b     = bh >> 4;
    const int h     = bh & 15;
    const int t     = threadIdx.x;
    const int w     = t >> 6;              // wave 0..3
    const int lane  = t & 63;
    const int row16 = lane & 15;
    const int quad  = lane >> 4;

    const float* Qg = Q + (size_t)bh * 8192;
    const float* Kg = K + (size_t)bh * 8192;
    const float* Vg = V + (size_t)bh * 8192;

    // ---- Q: per-lane direct load of this lane's A-fragments (hi+lo) ----
    bf16x8 qh8[4], ql8[4];
    {
        const float* qrow = Qg + (size_t)(16 * w + row16) * 128 + 8 * quad;
#pragma unroll
        for (int kc = 0; kc < 4; ++kc) {
            const float4 f0 = *(const float4*)&qrow[32 * kc];
            const float4 f1 = *(const float4*)&qrow[32 * kc + 4];
            const float f[8] = { f0.x, f0.y, f0.z, f0.w, f1.x, f1.y, f1.z, f1.w };
            bf16x8 hi, lo;
#pragma unroll
            for (int j = 0; j < 8; ++j) {
                const bf16_t hv = (bf16_t)f[j];
                hi[j] = hv;
                lo[j] = (bf16_t)(f[j] - (float)hv);
            }
            qh8[kc] = hi;
            ql8[kc] = lo;
        }
    }

    // ---- K: load fp32 row-stripe, write KH (b128, swizzled), hold lo regs ----
    // thread t -> row r = t>>2, cols [32*(t&3), +32) = 4 chunks of 8.
    const int r   = t >> 2;
    const int c0q = (t & 3) * 4;          // chunk index base (c0/8)
    const int rsw = r & 7;
    bf16x8 klo[4];
    int kaddr[4];
#pragma unroll
    for (int jc = 0; jc < 4; ++jc)
        kaddr[jc] = r * 128 + (((c0q + jc) ^ rsw) << 3);
    {
#pragma unroll
        for (int jc = 0; jc < 4; ++jc) {
            const float4 f0 = *(const float4*)&Kg[r * 128 + 8 * (c0q + jc)];
            const float4 f1 = *(const float4*)&Kg[r * 128 + 8 * (c0q + jc) + 4];
            const float f[8] = { f0.x, f0.y, f0.z, f0.w, f1.x, f1.y, f1.z, f1.w };
            bf16x8 hi, lo;
#pragma unroll
            for (int j = 0; j < 8; ++j) {
                const bf16_t hv = (bf16_t)f[j];
                hi[j] = hv;
                lo[j] = (bf16_t)(f[j] - (float)hv);
            }
            *(bf16x8*)&Kb[kaddr[jc]] = hi;
            klo[jc] = lo;
        }
    }

    __syncthreads();   // B1: KH staged

    // ---- scores vs KH: Qh*KH then Ql*KH (ql8 dies here) ----
    f32x4 accS[4];
#pragma unroll
    for (int ni = 0; ni < 4; ++ni) accS[ni] = (f32x4){0.f, 0.f, 0.f, 0.f};
    const int bsw = row16 & 7;

#define SPASS(AREG)                                                            \
    {                                                                          \
        _Pragma("unroll")                                                      \
        for (int kc = 0; kc < 4; ++kc) {                                       \
            const bf16x8 a = AREG[kc];                                         \
            _Pragma("unroll")                                                  \
            for (int ni = 0; ni < 4; ++ni) {                                   \
                const bf16x8 bb = *(const bf16x8*)&Kb[(16 * ni + row16) * 128  \
                                       + ((((4 * kc + quad) ^ bsw)) << 3)];    \
                accS[ni] = __builtin_amdgcn_mfma_f32_16x16x32_bf16(a, bb, accS[ni], 0, 0, 0); \
            }                                                                  \
        }                                                                      \
    }

    __builtin_amdgcn_s_setprio(1);
    SPASS(qh8)      // Qh * Kh
    SPASS(ql8)      // Ql * Kh
    __builtin_amdgcn_s_setprio(0);

    // ---- V: issue loads NOW (mid-kernel burst), convert, stage Vt ----
    __builtin_amdgcn_sched_barrier(0);
    {
        const int s = lane;
#pragma unroll
        for (int j = 0; j < 8; ++j) {
            const int d0 = 32 * w + 4 * j;
            const float4 f = *(const float4*)&Vg[(size_t)s * 128 + d0];
            const float ff[4] = { f.x, f.y, f.z, f.w };
#pragma unroll
            for (int i = 0; i < 4; ++i) {
                const int d = d0 + i;
                Vt[d * 64 + ((((s >> 3) ^ (d & 7))) << 3) + (s & 7)] = (bf16_t)ff[i];
            }
        }
    }

    __syncthreads();   // B2: all KH reads done -> Kb reusable

    // ---- restage K: KL from held lo regs ----
#pragma unroll
    for (int jc = 0; jc < 4; ++jc)
        *(bf16x8*)&Kb[kaddr[jc]] = klo[jc];

    __syncthreads();   // B3: KL staged

    __builtin_amdgcn_s_setprio(1);
    SPASS(qh8)      // Qh * Kl   ((l,l) term ~2^-18 relative — negligible)
    __builtin_amdgcn_s_setprio(0);

    // ---- softmax fully in-register ----
    // lane holds S[l=16w+4q+rr][s=16ni+row16]
    float e[4][4];      // e[ni][rr]
    float inv_[4];
    const float cs = 0.1f * 1.44269504088896f;   // scale * log2(e)
#pragma unroll
    for (int rr = 0; rr < 4; ++rr) {
        float m = fmaxf(fmaxf(accS[0][rr], accS[1][rr]),
                        fmaxf(accS[2][rr], accS[3][rr]));
        m = fmaxf(m, __shfl_xor(m, 1));
        m = fmaxf(m, __shfl_xor(m, 2));
        m = fmaxf(m, __shfl_xor(m, 4));
        m = fmaxf(m, __shfl_xor(m, 8));
        float s0 = 0.f;
#pragma unroll
        for (int ni = 0; ni < 4; ++ni) {
            const float ev = exp2f((accS[ni][rr] - m) * cs);
            e[ni][rr] = ev;
            s0 += ev;
        }
        s0 += __shfl_xor(s0, 1);
        s0 += __shfl_xor(s0, 2);
        s0 += __shfl_xor(s0, 4);
        s0 += __shfl_xor(s0, 8);
        inv_[rr] = 1.0f / s0;    // folded in after PV
    }

    __syncthreads();   // B4: all KL reads done -> Ps overlay safe; Vt published

    // ---- P (unnormalized, bf16) -> Ps (Kb region, wave-local rows) ----
#pragma unroll
    for (int rr = 0; rr < 4; ++rr) {
        const int l   = 16 * w + 4 * quad + rr;
        const int lsw = l & 7;
#pragma unroll
        for (int ni = 0; ni < 4; ++ni) {
            const int s = 16 * ni + row16;
            Ps[l * 64 + ((((s >> 3) ^ lsw)) << 3) + (s & 7)] = (bf16_t)e[ni][rr];
        }
    }
    asm volatile("s_waitcnt lgkmcnt(0)" ::: "memory");
    __builtin_amdgcn_sched_barrier(0);

    // ---- O[l,d] = sum_s P[l,s] V[s,d] ----
    f32x4 accO[8];
#pragma unroll
    for (int ni = 0; ni < 8; ++ni) accO[ni] = (f32x4){0.f, 0.f, 0.f, 0.f};
    __builtin_amdgcn_s_setprio(1);
#pragma unroll
    for (int kb = 0; kb < 2; ++kb) {
        const bf16x8 a = *(const bf16x8*)&Ps[(16 * w + row16) * 64
                               + ((((4 * kb + quad) ^ bsw)) << 3)];
#pragma unroll
        for (int ni = 0; ni < 8; ++ni) {
            const bf16x8 bb = *(const bf16x8*)&Vt[(16 * ni + row16) * 64
                                   + ((((4 * kb + quad) ^ bsw)) << 3)];
            accO[ni] = __builtin_amdgcn_mfma_f32_16x16x32_bf16(a, bb, accO[ni], 0, 0, 0);
        }
    }
    __builtin_amdgcn_s_setprio(0);

    __syncthreads();   // B5: all PV reads of Vt done -> Ob overlay safe

    // ---- O -> Ob (Vt region, wave-local rows), scale by 1/sum ----
#pragma unroll
    for (int ni = 0; ni < 8; ++ni)
#pragma unroll
        for (int rr = 0; rr < 4; ++rr) {
            const int l = 16 * w + 4 * quad + rr;   // l&3 == rr
            const int d = 16 * ni + row16;
            Ob[l * 128 + ((((d >> 3) ^ (5 * rr))) << 3) + (d & 7)] =
                (bf16_t)(accO[ni][rr] * inv_[rr]);
        }
    asm volatile("s_waitcnt lgkmcnt(0)" ::: "memory");
    __builtin_amdgcn_sched_barrier(0);

    // ---- coalesced store of this wave's 16 rows (16B per lane) ----
    {
        const int lr = 16 * w + (lane >> 2);
        bf16_t* Xrow = X + (size_t)b * 131072 + (size_t)h * 128 + (size_t)lr * 2048;
#pragma unroll
        for (int jj = 0; jj < 4; ++jj) {
            const int c8 = (lane & 3) + 4 * jj;
            const bf16x8 v = *(const bf16x8*)&Ob[lr * 128 + ((c8 ^ (5 * (lr & 3))) << 3)];
            *(bf16x8*)&Xrow[8 * c8] = v;
        }
    }
}

// ---------------------------------------------------------------------------
// Kernel 3: out[m,n] = sum_k X[m,k] Wb[n,k] + bias[n]  (M=8192,N=2048,K=2048)
// 128x128 tile, BK=64, 256 thr, 4 blocks/CU, global_load_lds width 16.
// LDS tile [128 rows][8 chunks of 16B] with XOR swizzle p = q ^ (row&7):
// fragment reads hit all 32 banks evenly (conflict-free).
// Grid x = M-tiles so each XCD's X slice (4 MiB) stays L2-resident.
// ---------------------------------------------------------------------------
__global__ __launch_bounds__(256, 4) void gemm_kernel(const bf16_t* __restrict__ X,
                                                      const bf16_t* __restrict__ Wb,
                                                      const float* __restrict__ bias,
                                                      float* __restrict__ out) {
    __shared__ bf16_t As[128 * 64];   // 16 KiB
    __shared__ bf16_t Bs[128 * 64];   // 16 KiB

    const int t    = threadIdx.x;
    const int w    = t >> 6;
    const int lane = t & 63;
    const int row16 = lane & 15;
    const int quad  = lane >> 4;
    const int m0 = blockIdx.x * 128;   // x = M (XCD locality for X)
    const int n0 = blockIdx.y * 128;
    const int wm = w >> 1;             // 2x2 wave grid, each wave 64x64
    const int wn = w & 1;

    // staging: wave w stages rows [32w,32w+32) of each tile, 4 insts of 8 rows.
    // lane -> (row8 = lane>>3, q = lane&7); global col swizzled: 8*(q ^ row8)
    const int row8 = lane >> 3;
    const int scol = 8 * ((lane & 7) ^ (row8 & 7));
    const bf16_t* gA = X  + (size_t)(m0 + 32 * w + row8) * 2048 + scol;
    const bf16_t* gB = Wb + (size_t)(n0 + 32 * w + row8) * 2048 + scol;
    bf16_t* lA = &As[(32 * w) * 64];
    bf16_t* lB = &Bs[(32 * w) * 64];

    // fragment read offsets (elements), swizzled: row*64 + 8*((4*kk+quad)^(row&7))
    const int sw = row16 & 7;
    int aoff[4][2], boff[4][2];
#pragma unroll
    for (int mi = 0; mi < 4; ++mi)
#pragma unroll
        for (int kk = 0; kk < 2; ++kk) {
            const int ar = 64 * wm + 16 * mi + row16;
            const int br = 64 * wn + 16 * mi + row16;
            aoff[mi][kk] = ar * 64 + 8 * ((4 * kk + quad) ^ sw);
            boff[mi][kk] = br * 64 + 8 * ((4 * kk + quad) ^ sw);
        }

    f32x4 acc[4][4];
#pragma unroll
    for (int mi = 0; mi < 4; ++mi)
#pragma unroll
        for (int ni = 0; ni < 4; ++ni) acc[mi][ni] = (f32x4){0.f, 0.f, 0.f, 0.f};

    for (int kb = 0; kb < 32; ++kb) {
        const int k0 = kb * 64;
        __syncthreads();                       // previous compute done before overwrite
#pragma unroll
        for (int i = 0; i < 4; ++i) {
            gld_lds16(gA + (size_t)(8 * i) * 2048 + k0, lA + (8 * i) * 64);
            gld_lds16(gB + (size_t)(8 * i) * 2048 + k0, lB + (8 * i) * 64);
        }
        __syncthreads();                       // staged (compiler drains vmcnt)

#pragma unroll
        for (int kk = 0; kk < 2; ++kk) {
            bf16x8 a[4], bb[4];
#pragma unroll
            for (int mi = 0; mi < 4; ++mi) a[mi]  = *(const bf16x8*)&As[aoff[mi][kk]];
#pragma unroll
            for (int ni = 0; ni < 4; ++ni) bb[ni] = *(const bf16x8*)&Bs[boff[ni][kk]];
#pragma unroll
            for (int mi = 0; mi < 4; ++mi)
#pragma unroll
                for (int ni = 0; ni < 4; ++ni)
                    acc[mi][ni] = __builtin_amdgcn_mfma_f32_16x16x32_bf16(a[mi], bb[ni], acc[mi][ni], 0, 0, 0);
        }
    }

    // epilogue: add bias, store FP32
    const int nb = n0 + 64 * wn;
    float br[4];
#pragma unroll
    for (int ni = 0; ni < 4; ++ni) br[ni] = bias[nb + 16 * ni + row16];
#pragma unroll
    for (int mi = 0; mi < 4; ++mi)
#pragma unroll
        for (int ni = 0; ni < 4; ++ni)
#pragma unroll
            for (int rr = 0; rr < 4; ++rr) {
                const int m = m0 + 64 * wm + 16 * mi + 4 * quad + rr;
                const int n = nb + 16 * ni + row16;
                out[(size_t)m * 2048 + n] = acc[mi][ni][rr] + br[ni];
            }
}

// ---------------------------------------------------------------------------
extern "C" void kernel_launch(void* const* d_in, const int* in_sizes, int n_in,
                              void* d_out, int out_size, void* d_ws, size_t ws_size,
                              hipStream_t stream) {
    const float* Q    = (const float*)d_in[0];
    const float* K    = (const float*)d_in[1];
    const float* V    = (const float*)d_in[2];
    const float* W    = (const float*)d_in[3];
    const float* bias = (const float*)d_in[4];

    bf16_t* Xws = (bf16_t*)d_ws;                                    // 32 MiB
    bf16_t* Wb  = (bf16_t*)((char*)d_ws + (size_t)8192 * 2048 * 2); // 8 MiB
    float*  out = (float*)d_out;

    wconv_kernel<<<4096, 256, 0, stream>>>(W, Wb);
    attn_kernel<<<2048, 256, 0, stream>>>(Q, K, V, Xws);
    gemm_kernel<<<dim3(64, 16), 256, 0, stream>>>(Xws, Wb, bias, out);
}

// Round 5
// 299.673 us; speedup vs baseline: 1.1056x; 1.0189x over previous
//
#include <hip/hip_runtime.h>
#include <hip/hip_bf16.h>
#include <stdint.h>

typedef __bf16 bf16_t;
typedef __bf16 bf16x4 __attribute__((ext_vector_type(4)));
typedef __bf16 bf16x8 __attribute__((ext_vector_type(8)));
typedef float  f32x4  __attribute__((ext_vector_type(4)));

#define AS1 __attribute__((address_space(1)))
#define AS3 __attribute__((address_space(3)))

// async global->LDS, 16B per lane; lds dest = wave-uniform base + lane*16
__device__ __forceinline__ void gld_lds16(const void* gp, void* lp) {
    __builtin_amdgcn_global_load_lds((const AS1 unsigned int*)gp,
                                     (AS3 unsigned int*)lp, 16, 0, 0);
}

__device__ __forceinline__ bf16_t bhi(float v) { return (bf16_t)v; }
__device__ __forceinline__ bf16_t blo(float v) {
    return (bf16_t)(v - (float)((bf16_t)v));
}

// ---------------------------------------------------------------------------
// Kernel 1: W fp32 -> bf16
// ---------------------------------------------------------------------------
__global__ __launch_bounds__(256) void wconv_kernel(const float* __restrict__ W,
                                                    bf16_t* __restrict__ Wb) {
    const int i = (blockIdx.x * 256 + threadIdx.x) * 4;
    const float4 f = *(const float4*)&W[i];
    bf16x4 v = { (bf16_t)f.x, (bf16_t)f.y, (bf16_t)f.z, (bf16_t)f.w };
    *(bf16x4*)&Wb[i] = v;
}

// ---------------------------------------------------------------------------
// Kernel 2: attention per (b,h).  L=64, E=128.  fp32 in, bf16 X out.
//
// Round-5: round-4 structure, ONE change: __launch_bounds__(256,4) -> (256,3).
// Bound=4 made the allocator clamp to the 64-VGPR occupancy step; live set
// (~100: qh8/ql8/klo + accS + V-loads in flight) still spilled ~20MB write
// + ~10MB re-read (WRITE 53MB vs 33 ideal).  Bound=3 -> cap ~170, zero
// spill; occupancy stays ~4 blocks/CU (VGPR-limited), LDS 32KB.
// ---------------------------------------------------------------------------
__global__ __launch_bounds__(256, 3) void attn_kernel(const float* __restrict__ Q,
                                                      const float* __restrict__ K,
                                                      const float* __restrict__ V,
                                                      bf16_t* __restrict__ X) {
    // LDS plan (bytes):
    //   Kb : [0, 16384)      64x128 bf16 swz  (KH then KL) -> Ps overlay
    //   Vt : [16384, 32768)  128x64 bf16 swz  (V^T)        -> Ob overlay
    __shared__ __align__(16) char smem[32768];
    bf16_t* Kb = (bf16_t*)smem;
    bf16_t* Vt = (bf16_t*)(smem + 16384);
    bf16_t* Ps = (bf16_t*)smem;             // 64x64 swz, wave-local rows
    bf16_t* Ob = (bf16_t*)(smem + 16384);   // 64x128 swz, wave-local rows

    const int bh    = blockIdx.x;          // b*16 + h
    const int b     = bh >> 4;
    const int h     = bh & 15;
    const int t     = threadIdx.x;
    const int w     = t >> 6;              // wave 0..3
    const int lane  = t & 63;
    const int row16 = lane & 15;
    const int quad  = lane >> 4;

    const float* Qg = Q + (size_t)bh * 8192;
    const float* Kg = K + (size_t)bh * 8192;
    const float* Vg = V + (size_t)bh * 8192;

    // ---- Q: per-lane direct load of this lane's A-fragments (hi+lo) ----
    bf16x8 qh8[4], ql8[4];
    {
        const float* qrow = Qg + (size_t)(16 * w + row16) * 128 + 8 * quad;
#pragma unroll
        for (int kc = 0; kc < 4; ++kc) {
            const float4 f0 = *(const float4*)&qrow[32 * kc];
            const float4 f1 = *(const float4*)&qrow[32 * kc + 4];
            const float f[8] = { f0.x, f0.y, f0.z, f0.w, f1.x, f1.y, f1.z, f1.w };
            bf16x8 hi, lo;
#pragma unroll
            for (int j = 0; j < 8; ++j) {
                const bf16_t hv = (bf16_t)f[j];
                hi[j] = hv;
                lo[j] = (bf16_t)(f[j] - (float)hv);
            }
            qh8[kc] = hi;
            ql8[kc] = lo;
        }
    }

    // ---- K: load fp32 row-stripe, write KH (b128, swizzled), hold lo regs ----
    // thread t -> row r = t>>2, cols [32*(t&3), +32) = 4 chunks of 8.
    const int r   = t >> 2;
    const int c0q = (t & 3) * 4;          // chunk index base (c0/8)
    const int rsw = r & 7;
    bf16x8 klo[4];
    int kaddr[4];
#pragma unroll
    for (int jc = 0; jc < 4; ++jc)
        kaddr[jc] = r * 128 + (((c0q + jc) ^ rsw) << 3);
    {
#pragma unroll
        for (int jc = 0; jc < 4; ++jc) {
            const float4 f0 = *(const float4*)&Kg[r * 128 + 8 * (c0q + jc)];
            const float4 f1 = *(const float4*)&Kg[r * 128 + 8 * (c0q + jc) + 4];
            const float f[8] = { f0.x, f0.y, f0.z, f0.w, f1.x, f1.y, f1.z, f1.w };
            bf16x8 hi, lo;
#pragma unroll
            for (int j = 0; j < 8; ++j) {
                const bf16_t hv = (bf16_t)f[j];
                hi[j] = hv;
                lo[j] = (bf16_t)(f[j] - (float)hv);
            }
            *(bf16x8*)&Kb[kaddr[jc]] = hi;
            klo[jc] = lo;
        }
    }

    __syncthreads();   // B1: KH staged

    // ---- scores vs KH: Qh*KH then Ql*KH (ql8 dies here) ----
    f32x4 accS[4];
#pragma unroll
    for (int ni = 0; ni < 4; ++ni) accS[ni] = (f32x4){0.f, 0.f, 0.f, 0.f};
    const int bsw = row16 & 7;

#define SPASS(AREG)                                                            \
    {                                                                          \
        _Pragma("unroll")                                                      \
        for (int kc = 0; kc < 4; ++kc) {                                       \
            const bf16x8 a = AREG[kc];                                         \
            _Pragma("unroll")                                                  \
            for (int ni = 0; ni < 4; ++ni) {                                   \
                const bf16x8 bb = *(const bf16x8*)&Kb[(16 * ni + row16) * 128  \
                                       + ((((4 * kc + quad) ^ bsw)) << 3)];    \
                accS[ni] = __builtin_amdgcn_mfma_f32_16x16x32_bf16(a, bb, accS[ni], 0, 0, 0); \
            }                                                                  \
        }                                                                      \
    }

    __builtin_amdgcn_s_setprio(1);
    SPASS(qh8)      // Qh * Kh
    SPASS(ql8)      // Ql * Kh
    __builtin_amdgcn_s_setprio(0);

    // ---- V: issue loads NOW (mid-kernel burst), convert, stage Vt ----
    __builtin_amdgcn_sched_barrier(0);
    {
        const int s = lane;
#pragma unroll
        for (int j = 0; j < 8; ++j) {
            const int d0 = 32 * w + 4 * j;
            const float4 f = *(const float4*)&Vg[(size_t)s * 128 + d0];
            const float ff[4] = { f.x, f.y, f.z, f.w };
#pragma unroll
            for (int i = 0; i < 4; ++i) {
                const int d = d0 + i;
                Vt[d * 64 + ((((s >> 3) ^ (d & 7))) << 3) + (s & 7)] = (bf16_t)ff[i];
            }
        }
    }

    __syncthreads();   // B2: all KH reads done -> Kb reusable

    // ---- restage K: KL from held lo regs ----
#pragma unroll
    for (int jc = 0; jc < 4; ++jc)
        *(bf16x8*)&Kb[kaddr[jc]] = klo[jc];

    __syncthreads();   // B3: KL staged

    __builtin_amdgcn_s_setprio(1);
    SPASS(qh8)      // Qh * Kl   ((l,l) term ~2^-18 relative — negligible)
    __builtin_amdgcn_s_setprio(0);

    // ---- softmax fully in-register ----
    // lane holds S[l=16w+4q+rr][s=16ni+row16]
    float e[4][4];      // e[ni][rr]
    float inv_[4];
    const float cs = 0.1f * 1.44269504088896f;   // scale * log2(e)
#pragma unroll
    for (int rr = 0; rr < 4; ++rr) {
        float m = fmaxf(fmaxf(accS[0][rr], accS[1][rr]),
                        fmaxf(accS[2][rr], accS[3][rr]));
        m = fmaxf(m, __shfl_xor(m, 1));
        m = fmaxf(m, __shfl_xor(m, 2));
        m = fmaxf(m, __shfl_xor(m, 4));
        m = fmaxf(m, __shfl_xor(m, 8));
        float s0 = 0.f;
#pragma unroll
        for (int ni = 0; ni < 4; ++ni) {
            const float ev = exp2f((accS[ni][rr] - m) * cs);
            e[ni][rr] = ev;
            s0 += ev;
        }
        s0 += __shfl_xor(s0, 1);
        s0 += __shfl_xor(s0, 2);
        s0 += __shfl_xor(s0, 4);
        s0 += __shfl_xor(s0, 8);
        inv_[rr] = 1.0f / s0;    // folded in after PV
    }

    __syncthreads();   // B4: all KL reads done -> Ps overlay safe; Vt published

    // ---- P (unnormalized, bf16) -> Ps (Kb region, wave-local rows) ----
#pragma unroll
    for (int rr = 0; rr < 4; ++rr) {
        const int l   = 16 * w + 4 * quad + rr;
        const int lsw = l & 7;
#pragma unroll
        for (int ni = 0; ni < 4; ++ni) {
            const int s = 16 * ni + row16;
            Ps[l * 64 + ((((s >> 3) ^ lsw)) << 3) + (s & 7)] = (bf16_t)e[ni][rr];
        }
    }
    asm volatile("s_waitcnt lgkmcnt(0)" ::: "memory");
    __builtin_amdgcn_sched_barrier(0);

    // ---- O[l,d] = sum_s P[l,s] V[s,d] ----
    f32x4 accO[8];
#pragma unroll
    for (int ni = 0; ni < 8; ++ni) accO[ni] = (f32x4){0.f, 0.f, 0.f, 0.f};
    __builtin_amdgcn_s_setprio(1);
#pragma unroll
    for (int kb = 0; kb < 2; ++kb) {
        const bf16x8 a = *(const bf16x8*)&Ps[(16 * w + row16) * 64
                               + ((((4 * kb + quad) ^ bsw)) << 3)];
#pragma unroll
        for (int ni = 0; ni < 8; ++ni) {
            const bf16x8 bb = *(const bf16x8*)&Vt[(16 * ni + row16) * 64
                                   + ((((4 * kb + quad) ^ bsw)) << 3)];
            accO[ni] = __builtin_amdgcn_mfma_f32_16x16x32_bf16(a, bb, accO[ni], 0, 0, 0);
        }
    }
    __builtin_amdgcn_s_setprio(0);

    __syncthreads();   // B5: all PV reads of Vt done -> Ob overlay safe

    // ---- O -> Ob (Vt region, wave-local rows), scale by 1/sum ----
#pragma unroll
    for (int ni = 0; ni < 8; ++ni)
#pragma unroll
        for (int rr = 0; rr < 4; ++rr) {
            const int l = 16 * w + 4 * quad + rr;   // l&3 == rr
            const int d = 16 * ni + row16;
            Ob[l * 128 + ((((d >> 3) ^ (5 * rr))) << 3) + (d & 7)] =
                (bf16_t)(accO[ni][rr] * inv_[rr]);
        }
    asm volatile("s_waitcnt lgkmcnt(0)" ::: "memory");
    __builtin_amdgcn_sched_barrier(0);

    // ---- coalesced store of this wave's 16 rows (16B per lane) ----
    {
        const int lr = 16 * w + (lane >> 2);
        bf16_t* Xrow = X + (size_t)b * 131072 + (size_t)h * 128 + (size_t)lr * 2048;
#pragma unroll
        for (int jj = 0; jj < 4; ++jj) {
            const int c8 = (lane & 3) + 4 * jj;
            const bf16x8 v = *(const bf16x8*)&Ob[lr * 128 + ((c8 ^ (5 * (lr & 3))) << 3)];
            *(bf16x8*)&Xrow[8 * c8] = v;
        }
    }
}

// ---------------------------------------------------------------------------
// Kernel 3: out[m,n] = sum_k X[m,k] Wb[n,k] + bias[n]  (M=8192,N=2048,K=2048)
// 128x128 tile, BK=64, 256 thr, global_load_lds width 16.
// Round-5: __launch_bounds__(256,4) -> (256,3).  Live set (acc 64 + frag 32
// + offsets/addr ~40 ≈ 130-150; m97's equivalent compiled to 164 VGPR)
// exceeds the 128-reg cap bound=4 imposes -> likely per-K-step scratch
// spill.  Bound=3 (cap ~170) matches the m97-structure's natural
// allocation (912 TF at 3 waves/SIMD).
// LDS tile [128 rows][8 chunks of 16B] with XOR swizzle p = q ^ (row&7):
// fragment reads hit all 32 banks evenly (conflict-free).
// Grid x = M-tiles so each XCD's X slice (4 MiB) stays L2-resident.
// ---------------------------------------------------------------------------
__global__ __launch_bounds__(256, 3) void gemm_kernel(const bf16_t* __restrict__ X,
                                                      const bf16_t* __restrict__ Wb,
                                                      const float* __restrict__ bias,
                                                      float* __restrict__ out) {
    __shared__ bf16_t As[128 * 64];   // 16 KiB
    __shared__ bf16_t Bs[128 * 64];   // 16 KiB

    const int t    = threadIdx.x;
    const int w    = t >> 6;
    const int lane = t & 63;
    const int row16 = lane & 15;
    const int quad  = lane >> 4;
    const int m0 = blockIdx.x * 128;   // x = M (XCD locality for X)
    const int n0 = blockIdx.y * 128;
    const int wm = w >> 1;             // 2x2 wave grid, each wave 64x64
    const int wn = w & 1;

    // staging: wave w stages rows [32w,32w+32) of each tile, 4 insts of 8 rows.
    // lane -> (row8 = lane>>3, q = lane&7); global col swizzled: 8*(q ^ row8)
    const int row8 = lane >> 3;
    const int scol = 8 * ((lane & 7) ^ (row8 & 7));
    const bf16_t* gA = X  + (size_t)(m0 + 32 * w + row8) * 2048 + scol;
    const bf16_t* gB = Wb + (size_t)(n0 + 32 * w + row8) * 2048 + scol;
    bf16_t* lA = &As[(32 * w) * 64];
    bf16_t* lB = &Bs[(32 * w) * 64];

    // fragment read offsets (elements), swizzled: row*64 + 8*((4*kk+quad)^(row&7))
    const int sw = row16 & 7;
    int aoff[4][2], boff[4][2];
#pragma unroll
    for (int mi = 0; mi < 4; ++mi)
#pragma unroll
        for (int kk = 0; kk < 2; ++kk) {
            const int ar = 64 * wm + 16 * mi + row16;
            const int br = 64 * wn + 16 * mi + row16;
            aoff[mi][kk] = ar * 64 + 8 * ((4 * kk + quad) ^ sw);
            boff[mi][kk] = br * 64 + 8 * ((4 * kk + quad) ^ sw);
        }

    f32x4 acc[4][4];
#pragma unroll
    for (int mi = 0; mi < 4; ++mi)
#pragma unroll
        for (int ni = 0; ni < 4; ++ni) acc[mi][ni] = (f32x4){0.f, 0.f, 0.f, 0.f};

    for (int kb = 0; kb < 32; ++kb) {
        const int k0 = kb * 64;
        __syncthreads();                       // previous compute done before overwrite
#pragma unroll
        for (int i = 0; i < 4; ++i) {
            gld_lds16(gA + (size_t)(8 * i) * 2048 + k0, lA + (8 * i) * 64);
            gld_lds16(gB + (size_t)(8 * i) * 2048 + k0, lB + (8 * i) * 64);
        }
        __syncthreads();                       // staged (compiler drains vmcnt)

#pragma unroll
        for (int kk = 0; kk < 2; ++kk) {
            bf16x8 a[4], bb[4];
#pragma unroll
            for (int mi = 0; mi < 4; ++mi) a[mi]  = *(const bf16x8*)&As[aoff[mi][kk]];
#pragma unroll
            for (int ni = 0; ni < 4; ++ni) bb[ni] = *(const bf16x8*)&Bs[boff[ni][kk]];
#pragma unroll
            for (int mi = 0; mi < 4; ++mi)
#pragma unroll
                for (int ni = 0; ni < 4; ++ni)
                    acc[mi][ni] = __builtin_amdgcn_mfma_f32_16x16x32_bf16(a[mi], bb[ni], acc[mi][ni], 0, 0, 0);
        }
    }

    // epilogue: add bias, store FP32
    const int nb = n0 + 64 * wn;
    float br[4];
#pragma unroll
    for (int ni = 0; ni < 4; ++ni) br[ni] = bias[nb + 16 * ni + row16];
#pragma unroll
    for (int mi = 0; mi < 4; ++mi)
#pragma unroll
        for (int ni = 0; ni < 4; ++ni)
#pragma unroll
            for (int rr = 0; rr < 4; ++rr) {
                const int m = m0 + 64 * wm + 16 * mi + 4 * quad + rr;
                const int n = nb + 16 * ni + row16;
                out[(size_t)m * 2048 + n] = acc[mi][ni][rr] + br[ni];
            }
}

// ---------------------------------------------------------------------------
extern "C" void kernel_launch(void* const* d_in, const int* in_sizes, int n_in,
                              void* d_out, int out_size, void* d_ws, size_t ws_size,
                              hipStream_t stream) {
    const float* Q    = (const float*)d_in[0];
    const float* K    = (const float*)d_in[1];
    const float* V    = (const float*)d_in[2];
    const float* W    = (const float*)d_in[3];
    const float* bias = (const float*)d_in[4];

    bf16_t* Xws = (bf16_t*)d_ws;                                    // 32 MiB
    bf16_t* Wb  = (bf16_t*)((char*)d_ws + (size_t)8192 * 2048 * 2); // 8 MiB
    float*  out = (float*)d_out;

    wconv_kernel<<<4096, 256, 0, stream>>>(W, Wb);
    attn_kernel<<<2048, 256, 0, stream>>>(Q, K, V, Xws);
    gemm_kernel<<<dim3(64, 16), 256, 0, stream>>>(Xws, Wb, bias, out);
}